// Round 2
// baseline (249.079 us; speedup 1.0000x reference)
//
#include <hip/hip_runtime.h>

#define O_ 2048
#define M_ 512
#define FIN 64
#define FMAS 64
#define DOUT 32
#define H_ 128
#define TD 96
#define NB_ 3
#define T_ 3

__device__ __forceinline__ float elu_f(float x) {
    return x > 0.f ? x : (__expf(x) - 1.f);
}

// ---------------------------------------------------------------------------
// K0: scalars k_e, c_e and basis-combined relation weights Wt[f][t*32+e]
// ---------------------------------------------------------------------------
__global__ void k0_setup(const float* __restrict__ e_w1, const float* __restrict__ e_b1,
                         const float* __restrict__ e_w2, const float* __restrict__ e_b2,
                         const float* __restrict__ coeff, const float* __restrict__ v,
                         float* __restrict__ ws_scal, float* __restrict__ ws_wt) {
    __shared__ float r1[128], r2[128];
    const int t = threadIdx.x;
    r1[t] = e_w1[t] * e_w2[t];
    r2[t] = e_b1[t] * e_w2[t];
    __syncthreads();
    for (int s = 64; s > 0; s >>= 1) {
        if (t < s) { r1[t] += r1[t + s]; r2[t] += r2[t + s]; }
        __syncthreads();
    }
    if (t == 0) { ws_scal[0] = r1[0]; ws_scal[1] = r2[0] + e_b2[0]; }
    for (int idx = t; idx < FMAS * TD; idx += 128) {
        int f = idx / TD, te = idx % TD;
        int tt = te / DOUT, e = te % DOUT;
        float s = 0.f;
        for (int nb = 0; nb < NB_; ++nb)
            s += coeff[tt * NB_ + nb] * v[(nb * FMAS + f) * DOUT + e];
        ws_wt[idx] = s;
    }
}

// ---------------------------------------------------------------------------
// K1: feat_opt = elu(h_opt @ w0_w1 + b1) @ w0_w2 + b2  -> d_out
// 64 rows/block, 512 threads. LDS-tiled fp32.
// ---------------------------------------------------------------------------
__global__ __launch_bounds__(512) void k1_featopt(
        const float* __restrict__ feat0, const int* __restrict__ bidx,
        const float* __restrict__ w1, const float* __restrict__ b1,
        const float* __restrict__ w2, const float* __restrict__ b2,
        float* __restrict__ out) {
    __shared__ float sAT[64 * 68];    // [k][row] transposed h_opt tile
    __shared__ float sW1[64 * 132];   // [k][h]
    __shared__ float sHT[128 * 69];   // [h][row]
    __shared__ float sW2[128 * 36];   // [h][e]
    const int t = threadIdx.x;
    const int tile = blockIdx.x;
    const int li = tile >> 5;               // 32 tiles of 64 rows per batch entry
    const int o0 = (tile & 31) * 64;
    const int bi = bidx[li];
    const float* abase = feat0 + ((long long)bi * O_ + o0) * FIN;

    for (int i = t; i < 1024; i += 512) {
        int r = i >> 4, c4 = (i & 15) * 4;
        float4 v4 = *(const float4*)(abase + (long long)r * FIN + c4);
        sAT[(c4 + 0) * 68 + r] = v4.x;
        sAT[(c4 + 1) * 68 + r] = v4.y;
        sAT[(c4 + 2) * 68 + r] = v4.z;
        sAT[(c4 + 3) * 68 + r] = v4.w;
    }
    for (int i = t; i < 2048; i += 512) {
        int k = i >> 5, c4 = (i & 31) * 4;
        *(float4*)&sW1[k * 132 + c4] = *(const float4*)(w1 + k * H_ + c4);
    }
    for (int i = t; i < 1024; i += 512) {
        int k = i >> 3, c4 = (i & 7) * 4;
        *(float4*)&sW2[k * 36 + c4] = *(const float4*)(w2 + k * DOUT + c4);
    }
    __syncthreads();

    // phase1: hidden[64][128]; thread = rg(16) x cg(32); rows r0..r0+3, cols cg+32j
    {
        const int rg = t >> 5, cg = t & 31;
        const int r0 = rg * 4;
        float acc[4][4];
        #pragma unroll
        for (int i = 0; i < 4; ++i)
            #pragma unroll
            for (int j = 0; j < 4; ++j) acc[i][j] = 0.f;
        for (int k = 0; k < 64; ++k) {
            float4 a4 = *(const float4*)&sAT[k * 68 + r0];
            float w0v = sW1[k * 132 + cg];
            float w1v = sW1[k * 132 + cg + 32];
            float w2v = sW1[k * 132 + cg + 64];
            float w3v = sW1[k * 132 + cg + 96];
            acc[0][0] += a4.x * w0v; acc[0][1] += a4.x * w1v; acc[0][2] += a4.x * w2v; acc[0][3] += a4.x * w3v;
            acc[1][0] += a4.y * w0v; acc[1][1] += a4.y * w1v; acc[1][2] += a4.y * w2v; acc[1][3] += a4.y * w3v;
            acc[2][0] += a4.z * w0v; acc[2][1] += a4.z * w1v; acc[2][2] += a4.z * w2v; acc[2][3] += a4.z * w3v;
            acc[3][0] += a4.w * w0v; acc[3][1] += a4.w * w1v; acc[3][2] += a4.w * w2v; acc[3][3] += a4.w * w3v;
        }
        #pragma unroll
        for (int i = 0; i < 4; ++i)
            #pragma unroll
            for (int j = 0; j < 4; ++j) {
                int h = cg + 32 * j;
                sHT[h * 69 + r0 + i] = elu_f(acc[i][j] + b1[h]);
            }
    }
    __syncthreads();

    // phase2: out[64][32]; thread = rg(32) x cg(16); rows r0..r0+1, cols cg, cg+16
    {
        const int rg = t >> 4, cg = t & 15;
        const int r0 = rg * 2;
        float a00 = 0.f, a01 = 0.f, a10 = 0.f, a11 = 0.f;
        for (int k = 0; k < 128; ++k) {
            float h0 = sHT[k * 69 + r0];
            float h1 = sHT[k * 69 + r0 + 1];
            float w0v = sW2[k * 36 + cg];
            float w1v = sW2[k * 36 + cg + 16];
            a00 += h0 * w0v; a01 += h0 * w1v;
            a10 += h1 * w0v; a11 += h1 * w1v;
        }
        long long row0 = (long long)tile * 64 + r0;
        out[row0 * DOUT + cg]            = a00 + b2[cg];
        out[row0 * DOUT + cg + 16]       = a01 + b2[cg + 16];
        out[(row0 + 1) * DOUT + cg]      = a10 + b2[cg];
        out[(row0 + 1) * DOUT + cg + 16] = a11 + b2[cg + 16];
    }
}

// ---------------------------------------------------------------------------
// K2: agg[r][f] = sum_m w(r,m) * h_mas[bi][m][f]
// 128 rows/block, 256 threads (4 waves). lane = f. h_mas m-tile held in
// registers (bb[64]); w tile staged transposed+XOR-swizzled in LDS and
// consumed as float4 broadcasts (4 rows per read).
// ---------------------------------------------------------------------------
__global__ __launch_bounds__(256) void k2_agg(
        const float* __restrict__ feat2, const int* __restrict__ adj,
        const float* __restrict__ hmas, const int* __restrict__ bidx,
        const float* __restrict__ scal, float* __restrict__ agg) {
    __shared__ float sWT[64 * 128];   // [m][row-swizzled]
    const int t = threadIdx.x;
    const int lane = t & 63;
    const int wid = t >> 6;
    const int tile = blockIdx.x;
    const int li = tile >> 4;               // 16 tiles of 128 rows per batch entry
    const int o0 = (tile & 15) * 128;
    const int bi = bidx[li];
    const float ke = scal[0], ce = scal[1];
    const float* f2b = feat2 + ((long long)bi * O_ + o0) * M_;
    const int*   adb = adj   + ((long long)bi * O_ + o0) * M_;
    const float* hb  = hmas  + (long long)bi * M_ * FMAS;

    float acc[4][8];
    #pragma unroll
    for (int c = 0; c < 4; ++c)
        #pragma unroll
        for (int i = 0; i < 8; ++i) acc[c][i] = 0.f;

    for (int kt = 0; kt < 8; ++kt) {
        const int m0 = kt * 64;
        __syncthreads();
        // stage w tile: 128 rows x 64 m -> sWT[m][swz(row)]
        #pragma unroll
        for (int jj = 0; jj < 8; ++jj) {
            int i = t + jj * 256;
            int row = i >> 4;
            int mq = (i & 15) * 4;
            float4 e4 = *(const float4*)(f2b + (long long)row * M_ + m0 + mq);
            int4   a4 = *(const int4*)  (adb + (long long)row * M_ + m0 + mq);
            int rq = row >> 2, rl = row & 3;
            float w0v = (a4.x == 1) ? e4.x * ke + ce : 0.f;
            float w1v = (a4.y == 1) ? e4.y * ke + ce : 0.f;
            float w2v = (a4.z == 1) ? e4.z * ke + ce : 0.f;
            float w3v = (a4.w == 1) ? e4.w * ke + ce : 0.f;
            sWT[(mq + 0) * 128 + ((rq ^ ((mq + 0) & 31)) << 2) + rl] = w0v;
            sWT[(mq + 1) * 128 + ((rq ^ ((mq + 1) & 31)) << 2) + rl] = w1v;
            sWT[(mq + 2) * 128 + ((rq ^ ((mq + 2) & 31)) << 2) + rl] = w2v;
            sWT[(mq + 3) * 128 + ((rq ^ ((mq + 3) & 31)) << 2) + rl] = w3v;
        }
        __syncthreads();
        // h_mas m-tile into registers: bb[j] = h_mas[m0+j][lane]
        float bb[64];
        #pragma unroll
        for (int j = 0; j < 64; ++j)
            bb[j] = hb[(long long)(m0 + j) * FMAS + lane];
        // wave wid owns rows [wid*32, wid*32+32), 4 chunks of 8 rows
        #pragma unroll
        for (int c = 0; c < 4; ++c) {
            const int r0 = wid * 32 + c * 8;
            const int rq0 = r0 >> 2;
            #pragma unroll
            for (int j = 0; j < 64; ++j) {
                const float4 wa = *(const float4*)&sWT[j * 128 + ((rq0 ^ (j & 31)) << 2)];
                const float4 wb = *(const float4*)&sWT[j * 128 + (((rq0 + 1) ^ (j & 31)) << 2)];
                acc[c][0] += wa.x * bb[j];
                acc[c][1] += wa.y * bb[j];
                acc[c][2] += wa.z * bb[j];
                acc[c][3] += wa.w * bb[j];
                acc[c][4] += wb.x * bb[j];
                acc[c][5] += wb.y * bb[j];
                acc[c][6] += wb.z * bb[j];
                acc[c][7] += wb.w * bb[j];
            }
        }
    }
    const long long rb = (long long)tile * 128;
    #pragma unroll
    for (int c = 0; c < 4; ++c)
        #pragma unroll
        for (int i = 0; i < 8; ++i)
            agg[(rb + wid * 32 + c * 8 + i) * 64 + lane] = acc[c][i];
}

// ---------------------------------------------------------------------------
// K3: typed = agg @ Wt ; mas_w = elu(typed @ om_w1 + b1) @ om_w2 + b2 ;
//     out = leaky_relu(feat_opt + mas_w)   (in-place on d_out)
// 64 rows/block, 512 threads.
// ---------------------------------------------------------------------------
__global__ __launch_bounds__(512) void k3_rest(
        const float* __restrict__ aggws, const float* __restrict__ wt,
        const float* __restrict__ om_w1, const float* __restrict__ om_b1,
        const float* __restrict__ om_w2, const float* __restrict__ om_b2,
        float* __restrict__ out) {
    __shared__ float sAgg[64 * 65];
    __shared__ float sWt[64 * 96];
    __shared__ float sTy[64 * 97];
    __shared__ float sOm1[96 * 128];
    __shared__ float sOm2[128];
    __shared__ float sB1[128];
    __shared__ float sPart[64 * 33];
    __shared__ float sMw[64];
    const int t = threadIdx.x;
    const long long tile = blockIdx.x;

    for (int i = t; i < 1024; i += 512) {
        int r = i >> 4, f4 = (i & 15) * 4;
        float4 v4 = *(const float4*)(aggws + (tile * 64 + r) * 64 + f4);
        sAgg[r * 65 + f4 + 0] = v4.x;
        sAgg[r * 65 + f4 + 1] = v4.y;
        sAgg[r * 65 + f4 + 2] = v4.z;
        sAgg[r * 65 + f4 + 3] = v4.w;
    }
    for (int i = t; i < 1536; i += 512)
        *(float4*)&sWt[i * 4] = *(const float4*)(wt + i * 4);
    for (int i = t; i < 3072; i += 512)
        *(float4*)&sOm1[i * 4] = *(const float4*)(om_w1 + i * 4);
    if (t < 128) { sOm2[t] = om_w2[t]; sB1[t] = om_b1[t]; }
    __syncthreads();

    // phase2: typed[64][96]; thread = rg(32) x tg(16); rows r0..r0+1, te0..te0+5
    {
        const int rg = t >> 4, tg = t & 15;
        const int r0 = rg * 2, te0 = tg * 6;
        float acc0[6], acc1[6];
        #pragma unroll
        for (int j = 0; j < 6; ++j) { acc0[j] = 0.f; acc1[j] = 0.f; }
        for (int k = 0; k < 64; ++k) {
            float a0 = sAgg[r0 * 65 + k];
            float a1 = sAgg[(r0 + 1) * 65 + k];
            #pragma unroll
            for (int j = 0; j < 6; ++j) {
                float w = sWt[k * 96 + te0 + j];
                acc0[j] += a0 * w;
                acc1[j] += a1 * w;
            }
        }
        #pragma unroll
        for (int j = 0; j < 6; ++j) {
            sTy[r0 * 97 + te0 + j]       = acc0[j];
            sTy[(r0 + 1) * 97 + te0 + j] = acc1[j];
        }
    }
    __syncthreads();

    // phase3: hidden[64][128] + partial mas_w; thread = rg(16) x hg(32)
    {
        const int rg = t >> 5, hg = t & 31;
        const int r0 = rg * 4;
        float acc[4][4];
        #pragma unroll
        for (int i = 0; i < 4; ++i)
            #pragma unroll
            for (int j = 0; j < 4; ++j) acc[i][j] = 0.f;
        for (int k = 0; k < 96; ++k) {
            float a0 = sTy[r0 * 97 + k];
            float a1 = sTy[(r0 + 1) * 97 + k];
            float a2 = sTy[(r0 + 2) * 97 + k];
            float a3 = sTy[(r0 + 3) * 97 + k];
            float w0v = sOm1[k * 128 + hg];
            float w1v = sOm1[k * 128 + hg + 32];
            float w2v = sOm1[k * 128 + hg + 64];
            float w3v = sOm1[k * 128 + hg + 96];
            acc[0][0] += a0 * w0v; acc[0][1] += a0 * w1v; acc[0][2] += a0 * w2v; acc[0][3] += a0 * w3v;
            acc[1][0] += a1 * w0v; acc[1][1] += a1 * w1v; acc[1][2] += a1 * w2v; acc[1][3] += a1 * w3v;
            acc[2][0] += a2 * w0v; acc[2][1] += a2 * w1v; acc[2][2] += a2 * w2v; acc[2][3] += a2 * w3v;
            acc[3][0] += a3 * w0v; acc[3][1] += a3 * w1v; acc[3][2] += a3 * w2v; acc[3][3] += a3 * w3v;
        }
        #pragma unroll
        for (int i = 0; i < 4; ++i) {
            float s = 0.f;
            #pragma unroll
            for (int j = 0; j < 4; ++j) {
                int h = hg + 32 * j;
                s += elu_f(acc[i][j] + sB1[h]) * sOm2[h];
            }
            sPart[(r0 + i) * 33 + hg] = s;
        }
    }
    __syncthreads();
    if (t < 64) {
        float s = 0.f;
        for (int j = 0; j < 32; ++j) s += sPart[t * 33 + j];
        sMw[t] = s + om_b2[0];
    }
    __syncthreads();
    // final: leaky_relu(feat_opt + mas_w), in-place float4
    {
        int row = t >> 3, e0 = (t & 7) * 4;
        float mw = sMw[row];
        float4* po = (float4*)(out + (tile * 64 + row) * DOUT + e0);
        float4 v4 = *po;
        v4.x += mw; v4.y += mw; v4.z += mw; v4.w += mw;
        v4.x = v4.x >= 0.f ? v4.x : 0.2f * v4.x;
        v4.y = v4.y >= 0.f ? v4.y : 0.2f * v4.y;
        v4.z = v4.z >= 0.f ? v4.z : 0.2f * v4.z;
        v4.w = v4.w >= 0.f ? v4.w : 0.2f * v4.w;
        *po = v4;
    }
}

// ---------------------------------------------------------------------------
extern "C" void kernel_launch(void* const* d_in, const int* in_sizes, int n_in,
                              void* d_out, int out_size, void* d_ws, size_t ws_size,
                              hipStream_t stream) {
    const float*     feat0 = (const float*)d_in[0];
    const float*     feat1 = (const float*)d_in[1];
    const float*     feat2 = (const float*)d_in[2];
    const int*       adj   = (const int*)d_in[3];
    const int*       bidx  = (const int*)d_in[4];   // harness delivers integers as int32
    const float*     w0_w1 = (const float*)d_in[5];
    const float*     w0_b1 = (const float*)d_in[6];
    const float*     w0_w2 = (const float*)d_in[7];
    const float*     w0_b2 = (const float*)d_in[8];
    const float*     v     = (const float*)d_in[9];
    const float*     coeff = (const float*)d_in[10];
    const float*     e_w1  = (const float*)d_in[11];
    const float*     e_b1  = (const float*)d_in[12];
    const float*     e_w2  = (const float*)d_in[13];
    const float*     e_b2  = (const float*)d_in[14];
    const float*     om_w1 = (const float*)d_in[15];
    const float*     om_b1 = (const float*)d_in[16];
    const float*     om_w2 = (const float*)d_in[17];
    const float*     om_b2 = (const float*)d_in[18];
    float* out = (float*)d_out;
    float* ws  = (float*)d_ws;

    const int bsel = in_sizes[4];          // 32
    float* ws_scal = ws;                   // 2 floats
    float* ws_wt   = ws + 16;              // 64*96 floats
    float* ws_agg  = ws + 8192;            // R*64 floats

    k0_setup<<<1, 128, 0, stream>>>(e_w1, e_b1, e_w2, e_b2, coeff, v, ws_scal, ws_wt);
    k1_featopt<<<bsel * 32, 512, 0, stream>>>(feat0, bidx, w0_w1, w0_b1, w0_b2 ? w0_w2 : w0_w2, w0_b2, out);
    k2_agg<<<bsel * 16, 256, 0, stream>>>(feat2, adj, feat1, bidx, ws_scal, ws_agg);
    k3_rest<<<bsel * 32, 512, 0, stream>>>(ws_agg, ws_wt, om_w1, om_b1, om_w2, om_b2, out);
}

// Round 4
// 172.997 us; speedup vs baseline: 1.4398x; 1.4398x over previous
//
#include <hip/hip_runtime.h>

#define O_ 2048
#define M_ 512
#define FIN 64
#define FMAS 64
#define DOUT 32
#define H_ 128
#define TD 96
#define NB_ 3
#define T_ 3

typedef __attribute__((ext_vector_type(4))) float f32x4;
typedef __attribute__((ext_vector_type(8))) short bf16x8;

__device__ __forceinline__ float elu_f(float x) {
    return x > 0.f ? x : (__expf(x) - 1.f);
}

// round-to-nearest-even f32 -> bf16 (no NaN inputs here)
__device__ __forceinline__ unsigned short f2b(float x) {
    union { float f; unsigned u; } uu; uu.f = x;
    unsigned r = uu.u + 0x7fffu + ((uu.u >> 16) & 1u);
    return (unsigned short)(r >> 16);
}
__device__ __forceinline__ float b2f(unsigned short s) {
    union { float f; unsigned u; } uu; uu.u = ((unsigned)s) << 16;
    return uu.f;
}

// ---------------------------------------------------------------------------
// K0: scalars k_e, c_e and basis-combined relation weights Wt[f][t*32+e]
// ---------------------------------------------------------------------------
__global__ void k0_setup(const float* __restrict__ e_w1, const float* __restrict__ e_b1,
                         const float* __restrict__ e_w2, const float* __restrict__ e_b2,
                         const float* __restrict__ coeff, const float* __restrict__ v,
                         float* __restrict__ ws_scal, float* __restrict__ ws_wt) {
    __shared__ float r1[128], r2[128];
    const int t = threadIdx.x;
    r1[t] = e_w1[t] * e_w2[t];
    r2[t] = e_b1[t] * e_w2[t];
    __syncthreads();
    for (int s = 64; s > 0; s >>= 1) {
        if (t < s) { r1[t] += r1[t + s]; r2[t] += r2[t + s]; }
        __syncthreads();
    }
    if (t == 0) { ws_scal[0] = r1[0]; ws_scal[1] = r2[0] + e_b2[0]; }
    for (int idx = t; idx < FMAS * TD; idx += 128) {
        int f = idx / TD, te = idx % TD;
        int tt = te / DOUT, e = te % DOUT;
        float s = 0.f;
        for (int nb = 0; nb < NB_; ++nb)
            s += coeff[tt * NB_ + nb] * v[(nb * FMAS + f) * DOUT + e];
        ws_wt[idx] = s;
    }
}

// ---------------------------------------------------------------------------
// K1: feat_opt = elu(h_opt @ w0_w1 + b1) @ w0_w2 + b2  -> d_out
// ---------------------------------------------------------------------------
__global__ __launch_bounds__(512) void k1_featopt(
        const float* __restrict__ feat0, const int* __restrict__ bidx,
        const float* __restrict__ w1, const float* __restrict__ b1,
        const float* __restrict__ w2, const float* __restrict__ b2,
        float* __restrict__ out) {
    __shared__ float sAT[64 * 68];    // [k][row]
    __shared__ float sW1[64 * 132];   // [k][h]
    __shared__ float sHT[128 * 69];   // [h][row]
    __shared__ float sW2[128 * 36];   // [h][e]
    const int t = threadIdx.x;
    const int tile = blockIdx.x;
    const int li = tile >> 5;
    const int o0 = (tile & 31) * 64;
    const int bi = bidx[li];
    const float* abase = feat0 + ((long long)bi * O_ + o0) * FIN;

    for (int i = t; i < 1024; i += 512) {
        int r = i >> 4, c4 = (i & 15) * 4;
        float4 v4 = *(const float4*)(abase + (long long)r * FIN + c4);
        sAT[(c4 + 0) * 68 + r] = v4.x;
        sAT[(c4 + 1) * 68 + r] = v4.y;
        sAT[(c4 + 2) * 68 + r] = v4.z;
        sAT[(c4 + 3) * 68 + r] = v4.w;
    }
    for (int i = t; i < 2048; i += 512) {
        int k = i >> 5, c4 = (i & 31) * 4;
        *(float4*)&sW1[k * 132 + c4] = *(const float4*)(w1 + k * H_ + c4);
    }
    for (int i = t; i < 1024; i += 512) {
        int k = i >> 3, c4 = (i & 7) * 4;
        *(float4*)&sW2[k * 36 + c4] = *(const float4*)(w2 + k * DOUT + c4);
    }
    __syncthreads();

    {
        const int rg = t >> 5, cg = t & 31;
        const int r0 = rg * 4;
        float acc[4][4];
        #pragma unroll
        for (int i = 0; i < 4; ++i)
            #pragma unroll
            for (int j = 0; j < 4; ++j) acc[i][j] = 0.f;
        for (int k = 0; k < 64; ++k) {
            float4 a4 = *(const float4*)&sAT[k * 68 + r0];
            float w0v = sW1[k * 132 + cg];
            float w1v = sW1[k * 132 + cg + 32];
            float w2v = sW1[k * 132 + cg + 64];
            float w3v = sW1[k * 132 + cg + 96];
            acc[0][0] += a4.x * w0v; acc[0][1] += a4.x * w1v; acc[0][2] += a4.x * w2v; acc[0][3] += a4.x * w3v;
            acc[1][0] += a4.y * w0v; acc[1][1] += a4.y * w1v; acc[1][2] += a4.y * w2v; acc[1][3] += a4.y * w3v;
            acc[2][0] += a4.z * w0v; acc[2][1] += a4.z * w1v; acc[2][2] += a4.z * w2v; acc[2][3] += a4.z * w3v;
            acc[3][0] += a4.w * w0v; acc[3][1] += a4.w * w1v; acc[3][2] += a4.w * w2v; acc[3][3] += a4.w * w3v;
        }
        #pragma unroll
        for (int i = 0; i < 4; ++i)
            #pragma unroll
            for (int j = 0; j < 4; ++j) {
                int h = cg + 32 * j;
                sHT[h * 69 + r0 + i] = elu_f(acc[i][j] + b1[h]);
            }
    }
    __syncthreads();

    {
        const int rg = t >> 4, cg = t & 15;
        const int r0 = rg * 2;
        float a00 = 0.f, a01 = 0.f, a10 = 0.f, a11 = 0.f;
        for (int k = 0; k < 128; ++k) {
            float h0 = sHT[k * 69 + r0];
            float h1 = sHT[k * 69 + r0 + 1];
            float w0v = sW2[k * 36 + cg];
            float w1v = sW2[k * 36 + cg + 16];
            a00 += h0 * w0v; a01 += h0 * w1v;
            a10 += h1 * w0v; a11 += h1 * w1v;
        }
        long long row0 = (long long)tile * 64 + r0;
        out[row0 * DOUT + cg]            = a00 + b2[cg];
        out[row0 * DOUT + cg + 16]       = a01 + b2[cg + 16];
        out[(row0 + 1) * DOUT + cg]      = a10 + b2[cg];
        out[(row0 + 1) * DOUT + cg + 16] = a11 + b2[cg + 16];
    }
}

// ---------------------------------------------------------------------------
// K2 (MFMA): agg[128xFMAS] = W[128xM] @ H[MxFMAS] per block.
// W = mask * (ke*feat2 + ce), computed on the fly, split hi/lo bf16,
// A-fragments loaded straight from global (coalesced 128B row segments).
// H staged once into LDS in fragment order (bf16 hi); no k-loop barriers.
// 256 threads = 4 waves; wave w owns rows [w*32, w*32+32), all 64 f.
// ---------------------------------------------------------------------------
__global__ __launch_bounds__(256) void k2_agg_mfma(
        const float* __restrict__ feat2, const int* __restrict__ adj,
        const float* __restrict__ hmas, const int* __restrict__ bidx,
        const float* __restrict__ scal, float* __restrict__ agg) {
    __shared__ bf16x8 Bh[4 * 16 * 64];   // [ftile][kstep][lane] -> 64 KiB
    const int t = threadIdx.x;
    const int l = t & 63;
    const int wid = t >> 6;
    const int tile = blockIdx.x;
    const int li = tile >> 4;
    const int o0 = (tile & 15) * 128;
    const int bi = bidx[li];
    const float ke = scal[0], ce = scal[1];
    const float* f2base = feat2 + ((long long)bi * O_ + o0) * M_;
    const int*   adb    = adj   + ((long long)bi * O_ + o0) * M_;
    const float* hb     = hmas  + (long long)bi * M_ * FMAS;

    // ---- stage H fragments (bf16 hi), once ----
    for (int e = t; e < 4096; e += 256) {
        const int le = e & 63;
        const int ks = (e >> 6) & 15;
        const int ft = e >> 10;
        const int g = le >> 4, c = le & 15;
        const float* src = hb + (ks * 32 + g * 8) * FMAS + ft * 16 + c;
        bf16x8 bv;
        #pragma unroll
        for (int j = 0; j < 8; ++j)
            bv[j] = (short)f2b(src[j * FMAS]);
        Bh[e] = bv;
    }
    __syncthreads();

    // ---- MFMA main loop ----
    const int g = l >> 4, c = l & 15;
    const int r0 = wid * 32;
    f32x4 acc[2][4];
    #pragma unroll
    for (int rt = 0; rt < 2; ++rt)
        #pragma unroll
        for (int ft = 0; ft < 4; ++ft)
            acc[rt][ft] = (f32x4){0.f, 0.f, 0.f, 0.f};

    const long long aoff = (long long)(r0 + c) * M_ + 8 * g;

    for (int ks = 0; ks < 16; ++ks) {
        const int k0 = ks * 32;
        bf16x8 ah[2], al[2];
        #pragma unroll
        for (int rt = 0; rt < 2; ++rt) {
            const float* fp = f2base + aoff + rt * 16 * M_ + k0;
            const int*   ap = adb    + aoff + rt * 16 * M_ + k0;
            float4 e0 = *(const float4*)fp;
            float4 e1 = *(const float4*)(fp + 4);
            int4   a0 = *(const int4*)ap;
            int4   a1 = *(const int4*)(ap + 4);
            float w[8];
            w[0] = (a0.x == 1) ? e0.x * ke + ce : 0.f;
            w[1] = (a0.y == 1) ? e0.y * ke + ce : 0.f;
            w[2] = (a0.z == 1) ? e0.z * ke + ce : 0.f;
            w[3] = (a0.w == 1) ? e0.w * ke + ce : 0.f;
            w[4] = (a1.x == 1) ? e1.x * ke + ce : 0.f;
            w[5] = (a1.y == 1) ? e1.y * ke + ce : 0.f;
            w[6] = (a1.z == 1) ? e1.z * ke + ce : 0.f;
            w[7] = (a1.w == 1) ? e1.w * ke + ce : 0.f;
            #pragma unroll
            for (int j = 0; j < 8; ++j) {
                unsigned short hi = f2b(w[j]);
                ah[rt][j] = (short)hi;
                al[rt][j] = (short)f2b(w[j] - b2f(hi));
            }
        }
        #pragma unroll
        for (int ft = 0; ft < 4; ++ft) {
            bf16x8 b = Bh[(ft * 16 + ks) * 64 + l];
            #pragma unroll
            for (int rt = 0; rt < 2; ++rt) {
                acc[rt][ft] = __builtin_amdgcn_mfma_f32_16x16x32_bf16(ah[rt], b, acc[rt][ft], 0, 0, 0);
                acc[rt][ft] = __builtin_amdgcn_mfma_f32_16x16x32_bf16(al[rt], b, acc[rt][ft], 0, 0, 0);
            }
        }
    }

    // ---- write agg: C/D layout col=lane&15, row=4*(lane>>4)+reg ----
    const long long rb = (long long)tile * 128 + r0;
    #pragma unroll
    for (int rt = 0; rt < 2; ++rt) {
        #pragma unroll
        for (int ft = 0; ft < 4; ++ft) {
            #pragma unroll
            for (int reg = 0; reg < 4; ++reg)
                agg[(rb + rt * 16 + g * 4 + reg) * 64 + ft * 16 + c] = acc[rt][ft][reg];
        }
    }
}

// ---------------------------------------------------------------------------
// K3: typed = agg @ Wt ; mas_w = elu(typed @ om_w1 + b1) @ om_w2 + b2 ;
//     out = leaky_relu(feat_opt + mas_w)   (in-place on d_out)
// ---------------------------------------------------------------------------
__global__ __launch_bounds__(512) void k3_rest(
        const float* __restrict__ aggws, const float* __restrict__ wt,
        const float* __restrict__ om_w1, const float* __restrict__ om_b1,
        const float* __restrict__ om_w2, const float* __restrict__ om_b2,
        float* __restrict__ out) {
    __shared__ float sAgg[64 * 65];
    __shared__ float sWt[64 * 96];
    __shared__ float sTy[64 * 97];
    __shared__ float sOm1[96 * 128];
    __shared__ float sOm2[128];
    __shared__ float sB1[128];
    __shared__ float sPart[64 * 33];
    __shared__ float sMw[64];
    const int t = threadIdx.x;
    const long long tile = blockIdx.x;

    for (int i = t; i < 1024; i += 512) {
        int r = i >> 4, f4 = (i & 15) * 4;
        float4 v4 = *(const float4*)(aggws + (tile * 64 + r) * 64 + f4);
        sAgg[r * 65 + f4 + 0] = v4.x;
        sAgg[r * 65 + f4 + 1] = v4.y;
        sAgg[r * 65 + f4 + 2] = v4.z;
        sAgg[r * 65 + f4 + 3] = v4.w;
    }
    for (int i = t; i < 1536; i += 512)
        *(float4*)&sWt[i * 4] = *(const float4*)(wt + i * 4);
    for (int i = t; i < 3072; i += 512)
        *(float4*)&sOm1[i * 4] = *(const float4*)(om_w1 + i * 4);
    if (t < 128) { sOm2[t] = om_w2[t]; sB1[t] = om_b1[t]; }
    __syncthreads();

    {
        const int rg = t >> 4, tg = t & 15;
        const int r0 = rg * 2, te0 = tg * 6;
        float acc0[6], acc1[6];
        #pragma unroll
        for (int j = 0; j < 6; ++j) { acc0[j] = 0.f; acc1[j] = 0.f; }
        for (int k = 0; k < 64; ++k) {
            float a0 = sAgg[r0 * 65 + k];
            float a1 = sAgg[(r0 + 1) * 65 + k];
            #pragma unroll
            for (int j = 0; j < 6; ++j) {
                float w = sWt[k * 96 + te0 + j];
                acc0[j] += a0 * w;
                acc1[j] += a1 * w;
            }
        }
        #pragma unroll
        for (int j = 0; j < 6; ++j) {
            sTy[r0 * 97 + te0 + j]       = acc0[j];
            sTy[(r0 + 1) * 97 + te0 + j] = acc1[j];
        }
    }
    __syncthreads();

    {
        const int rg = t >> 5, hg = t & 31;
        const int r0 = rg * 4;
        float acc[4][4];
        #pragma unroll
        for (int i = 0; i < 4; ++i)
            #pragma unroll
            for (int j = 0; j < 4; ++j) acc[i][j] = 0.f;
        for (int k = 0; k < 96; ++k) {
            float a0 = sTy[r0 * 97 + k];
            float a1 = sTy[(r0 + 1) * 97 + k];
            float a2 = sTy[(r0 + 2) * 97 + k];
            float a3 = sTy[(r0 + 3) * 97 + k];
            float w0v = sOm1[k * 128 + hg];
            float w1v = sOm1[k * 128 + hg + 32];
            float w2v = sOm1[k * 128 + hg + 64];
            float w3v = sOm1[k * 128 + hg + 96];
            acc[0][0] += a0 * w0v; acc[0][1] += a0 * w1v; acc[0][2] += a0 * w2v; acc[0][3] += a0 * w3v;
            acc[1][0] += a1 * w0v; acc[1][1] += a1 * w1v; acc[1][2] += a1 * w2v; acc[1][3] += a1 * w3v;
            acc[2][0] += a2 * w0v; acc[2][1] += a2 * w1v; acc[2][2] += a2 * w2v; acc[2][3] += a2 * w3v;
            acc[3][0] += a3 * w0v; acc[3][1] += a3 * w1v; acc[3][2] += a3 * w2v; acc[3][3] += a3 * w3v;
        }
        #pragma unroll
        for (int i = 0; i < 4; ++i) {
            float s = 0.f;
            #pragma unroll
            for (int j = 0; j < 4; ++j) {
                int h = hg + 32 * j;
                s += elu_f(acc[i][j] + sB1[h]) * sOm2[h];
            }
            sPart[(r0 + i) * 33 + hg] = s;
        }
    }
    __syncthreads();
    if (t < 64) {
        float s = 0.f;
        for (int j = 0; j < 32; ++j) s += sPart[t * 33 + j];
        sMw[t] = s + om_b2[0];
    }
    __syncthreads();
    {
        int row = t >> 3, e0 = (t & 7) * 4;
        float mw = sMw[row];
        float4* po = (float4*)(out + (tile * 64 + row) * DOUT + e0);
        float4 v4 = *po;
        v4.x += mw; v4.y += mw; v4.z += mw; v4.w += mw;
        v4.x = v4.x >= 0.f ? v4.x : 0.2f * v4.x;
        v4.y = v4.y >= 0.f ? v4.y : 0.2f * v4.y;
        v4.z = v4.z >= 0.f ? v4.z : 0.2f * v4.z;
        v4.w = v4.w >= 0.f ? v4.w : 0.2f * v4.w;
        *po = v4;
    }
}

// ---------------------------------------------------------------------------
extern "C" void kernel_launch(void* const* d_in, const int* in_sizes, int n_in,
                              void* d_out, int out_size, void* d_ws, size_t ws_size,
                              hipStream_t stream) {
    const float*     feat0 = (const float*)d_in[0];
    const float*     feat1 = (const float*)d_in[1];
    const float*     feat2 = (const float*)d_in[2];
    const int*       adj   = (const int*)d_in[3];
    const int*       bidx  = (const int*)d_in[4];   // harness delivers integers as int32
    const float*     w0_w1 = (const float*)d_in[5];
    const float*     w0_b1 = (const float*)d_in[6];
    const float*     w0_w2 = (const float*)d_in[7];
    const float*     w0_b2 = (const float*)d_in[8];
    const float*     v     = (const float*)d_in[9];
    const float*     coeff = (const float*)d_in[10];
    const float*     e_w1  = (const float*)d_in[11];
    const float*     e_b1  = (const float*)d_in[12];
    const float*     e_w2  = (const float*)d_in[13];
    const float*     e_b2  = (const float*)d_in[14];
    const float*     om_w1 = (const float*)d_in[15];
    const float*     om_b1 = (const float*)d_in[16];
    const float*     om_w2 = (const float*)d_in[17];
    const float*     om_b2 = (const float*)d_in[18];
    float* out = (float*)d_out;
    float* ws  = (float*)d_ws;

    const int bsel = in_sizes[4];          // 32
    float* ws_scal = ws;                   // 2 floats
    float* ws_wt   = ws + 16;              // 64*96 floats
    float* ws_agg  = ws + 8192;            // R*64 floats

    k0_setup<<<1, 128, 0, stream>>>(e_w1, e_b1, e_w2, e_b2, coeff, v, ws_scal, ws_wt);
    k1_featopt<<<bsel * 32, 512, 0, stream>>>(feat0, bidx, w0_w1, w0_b1, w0_w2, w0_b2, out);
    k2_agg_mfma<<<bsel * 16, 256, 0, stream>>>(feat2, adj, feat1, bidx, ws_scal, ws_agg);
    k3_rest<<<bsel * 32, 512, 0, stream>>>(ws_agg, ws_wt, om_w1, om_b1, om_w2, om_b2, out);
}

// Round 5
// 101.590 us; speedup vs baseline: 2.4518x; 1.7029x over previous
//
#include <hip/hip_runtime.h>

#define O_ 2048
#define M_ 512
#define FIN 64
#define FMAS 64
#define DOUT 32
#define H_ 128
#define TD 96
#define NB_ 3

typedef __attribute__((ext_vector_type(4))) float f32x4;
typedef __attribute__((ext_vector_type(8))) short bf16x8;

__device__ __forceinline__ float elu_f(float x) {
    return x > 0.f ? x : (__expf(x) - 1.f);
}
// round-to-nearest-even f32 -> bf16
__device__ __forceinline__ unsigned short f2b(float x) {
    union { float f; unsigned u; } uu; uu.f = x;
    unsigned r = uu.u + 0x7fffu + ((uu.u >> 16) & 1u);
    return (unsigned short)(r >> 16);
}
__device__ __forceinline__ float b2f(unsigned short s) {
    union { float f; unsigned u; } uu; uu.u = ((unsigned)s) << 16;
    return uu.f;
}

// ---------------------------------------------------------------------------
// K0: scalars k_e, c_e and basis-combined relation weights Wt[f][t*32+e]
// ---------------------------------------------------------------------------
__global__ void k0_setup(const float* __restrict__ e_w1, const float* __restrict__ e_b1,
                         const float* __restrict__ e_w2, const float* __restrict__ e_b2,
                         const float* __restrict__ coeff, const float* __restrict__ v,
                         float* __restrict__ ws_scal, float* __restrict__ ws_wt) {
    __shared__ float r1[128], r2[128];
    const int t = threadIdx.x;
    r1[t] = e_w1[t] * e_w2[t];
    r2[t] = e_b1[t] * e_w2[t];
    __syncthreads();
    for (int s = 64; s > 0; s >>= 1) {
        if (t < s) { r1[t] += r1[t + s]; r2[t] += r2[t + s]; }
        __syncthreads();
    }
    if (t == 0) { ws_scal[0] = r1[0]; ws_scal[1] = r2[0] + e_b2[0]; }
    for (int idx = t; idx < FMAS * TD; idx += 128) {
        int f = idx / TD, te = idx % TD;
        int tt = te / DOUT, e = te % DOUT;
        float s = 0.f;
        for (int nb = 0; nb < NB_; ++nb)
            s += coeff[tt * NB_ + nb] * v[(nb * FMAS + f) * DOUT + e];
        ws_wt[idx] = s;
    }
}

// ---------------------------------------------------------------------------
// MEGA kernel: per block = 128 rows of one selected batch entry.
// 256 threads = 4 waves; wave w owns rows [w*32, w*32+32).
// Phases: G1 feat_opt MLP (MFMA) -> G2 agg stream-GEMM (MFMA, k2 scheme)
//         -> G3 typed = agg@Wt -> G4 om-MLP -> epilogue leaky(fo+mas_w).
// MFMA conventions (validated in R4's k2):
//   A-frag lane(c,g): a[j]=A[c][g*8+j] ; B-frag: b[j]=B[g*8+j][c]
//   D: d[reg]=D[g*4+reg][c]   (c=lane&15, g=lane>>4, per 16x16x32 subtile)
// ---------------------------------------------------------------------------
__global__ __launch_bounds__(256) void mega(
        const float* __restrict__ feat0, const float* __restrict__ feat2,
        const int* __restrict__ adj, const float* __restrict__ hmas,
        const int* __restrict__ bidx, const float* __restrict__ scal,
        const float* __restrict__ wt,
        const float* __restrict__ w0w1, const float* __restrict__ w0b1,
        const float* __restrict__ w0w2, const float* __restrict__ w0b2,
        const float* __restrict__ om1, const float* __restrict__ omb1,
        const float* __restrict__ om2v, const float* __restrict__ omb2,
        float* __restrict__ out) {
    // phase-reused weight pool + per-wave scratch pool
    __shared__ __align__(16) char poolW[73728];
    __shared__ __align__(16) char poolS[45056];
    __shared__ float sB1w0[128], sB2w0[32], sB1om[128], sOm2[128], sKe[4];

    const int t = threadIdx.x;
    const int l = t & 63, w = t >> 6;
    const int c = l & 15, g = l >> 4;
    const int tile = blockIdx.x;
    const int li = tile >> 4;
    const int o0 = (tile & 15) * 128;
    const int bi = bidx[li];

    if (t < 128) { sB1w0[t] = w0b1[t]; sB1om[t] = omb1[t]; sOm2[t] = om2v[t]; }
    if (t < 32) sB2w0[t] = w0b2[t];
    if (t == 0) { sKe[0] = scal[0]; sKe[1] = scal[1]; sKe[2] = omb2[0]; }

    // ---- stage G1 weights (bf16 fragment order) ----
    bf16x8* sW1f = (bf16x8*)poolW;             // [8 nf][2 ks][64]
    bf16x8* sW2f = (bf16x8*)(poolW + 16384);   // [2 nf][4 ks][64]
    for (int e = t; e < 1024; e += 256) {
        int nf = e >> 7, ks = (e >> 6) & 1, le = e & 63;
        int cc = le & 15, gg = le >> 4;
        bf16x8 vv;
        #pragma unroll
        for (int j = 0; j < 8; ++j)
            vv[j] = (short)f2b(w0w1[(ks * 32 + gg * 8 + j) * H_ + nf * 16 + cc]);
        sW1f[e] = vv;
    }
    for (int e = t; e < 512; e += 256) {
        int nf = e >> 8, ks = (e >> 6) & 3, le = e & 63;
        int cc = le & 15, gg = le >> 4;
        bf16x8 vv;
        #pragma unroll
        for (int j = 0; j < 8; ++j)
            vv[j] = (short)f2b(w0w2[(ks * 32 + gg * 8 + j) * DOUT + nf * 16 + cc]);
        sW2f[e] = vv;
    }
    __syncthreads();

    // ---- G1: feat_opt = elu(feat0@W1+b1)@W2  (bias b2 added in epilogue) ----
    const float* f0b = feat0 + ((long long)bi * O_ + o0) * FIN;
    char* hidb = poolS + w * 11264;            // per-wave hidden scratch [32][272B]
    f32x4 fo[2][2];
    {
        f32x4 acc1[2][8];
        #pragma unroll
        for (int rf = 0; rf < 2; ++rf)
            #pragma unroll
            for (int nf = 0; nf < 8; ++nf) acc1[rf][nf] = (f32x4){0.f, 0.f, 0.f, 0.f};
        #pragma unroll
        for (int rf = 0; rf < 2; ++rf) {
            #pragma unroll
            for (int ks = 0; ks < 2; ++ks) {
                const float* ap = f0b + (w * 32 + rf * 16 + c) * FIN + ks * 32 + g * 8;
                float4 x0 = *(const float4*)ap;
                float4 x1 = *(const float4*)(ap + 4);
                bf16x8 a;
                a[0] = (short)f2b(x0.x); a[1] = (short)f2b(x0.y);
                a[2] = (short)f2b(x0.z); a[3] = (short)f2b(x0.w);
                a[4] = (short)f2b(x1.x); a[5] = (short)f2b(x1.y);
                a[6] = (short)f2b(x1.z); a[7] = (short)f2b(x1.w);
                #pragma unroll
                for (int nf = 0; nf < 8; ++nf)
                    acc1[rf][nf] = __builtin_amdgcn_mfma_f32_16x16x32_bf16(
                        a, sW1f[(nf * 2 + ks) * 64 + l], acc1[rf][nf], 0, 0, 0);
            }
        }
        // hidden (elu) -> per-wave LDS scratch, transposed for next A-frags
        #pragma unroll
        for (int rf = 0; rf < 2; ++rf)
            #pragma unroll
            for (int nf = 0; nf < 8; ++nf)
                #pragma unroll
                for (int reg = 0; reg < 4; ++reg) {
                    int row = rf * 16 + g * 4 + reg;
                    float hv = acc1[rf][nf][reg] + sB1w0[nf * 16 + c];
                    *(unsigned short*)(hidb + row * 272 + (nf * 16 + c) * 2) =
                        f2b(elu_f(hv));
                }
        #pragma unroll
        for (int rf = 0; rf < 2; ++rf)
            #pragma unroll
            for (int nf2 = 0; nf2 < 2; ++nf2) fo[rf][nf2] = (f32x4){0.f, 0.f, 0.f, 0.f};
        #pragma unroll
        for (int rf = 0; rf < 2; ++rf)
            #pragma unroll
            for (int ks = 0; ks < 4; ++ks) {
                bf16x8 a = *(const bf16x8*)(hidb + (rf * 16 + c) * 272 + ks * 64 + g * 16);
                #pragma unroll
                for (int nf2 = 0; nf2 < 2; ++nf2)
                    fo[rf][nf2] = __builtin_amdgcn_mfma_f32_16x16x32_bf16(
                        a, sW2f[(nf2 * 4 + ks) * 64 + l], fo[rf][nf2], 0, 0, 0);
            }
    }
    __syncthreads();   // done with sW1f/sW2f + hidden scratch

    // ---- stage H for G2 (bf16 hi, fragment order) ----
    bf16x8* sHf = (bf16x8*)poolW;              // [4 ft][16 ks][64]
    const float* hbm = hmas + (long long)bi * M_ * FMAS;
    for (int e = t; e < 4096; e += 256) {
        int ft = e >> 10, ks = (e >> 6) & 15, le = e & 63;
        int cc = le & 15, gg = le >> 4;
        const float* src = hbm + (ks * 32 + gg * 8) * FMAS + ft * 16 + cc;
        bf16x8 vv;
        #pragma unroll
        for (int j = 0; j < 8; ++j) vv[j] = (short)f2b(src[j * FMAS]);
        sHf[e] = vv;
    }
    __syncthreads();

    // ---- G2: agg = (mask*(ke*feat2+ce)) @ H   (A split hi/lo, B hi) ----
    const float ke = sKe[0], ce = sKe[1];
    const float* f2base = feat2 + ((long long)bi * O_ + o0) * M_;
    const int*   adb    = adj   + ((long long)bi * O_ + o0) * M_;
    f32x4 acc[2][4];
    #pragma unroll
    for (int rt = 0; rt < 2; ++rt)
        #pragma unroll
        for (int ft = 0; ft < 4; ++ft) acc[rt][ft] = (f32x4){0.f, 0.f, 0.f, 0.f};
    const long long aoff = (long long)(w * 32 + c) * M_ + 8 * g;
    for (int ks = 0; ks < 16; ++ks) {
        const int k0 = ks * 32;
        bf16x8 ah[2], al[2];
        #pragma unroll
        for (int rt = 0; rt < 2; ++rt) {
            const float* fp = f2base + aoff + rt * 16 * M_ + k0;
            const int*   ap = adb    + aoff + rt * 16 * M_ + k0;
            float4 e0 = *(const float4*)fp;
            float4 e1 = *(const float4*)(fp + 4);
            int4   a0 = *(const int4*)ap;
            int4   a1 = *(const int4*)(ap + 4);
            float wv[8];
            wv[0] = (a0.x == 1) ? e0.x * ke + ce : 0.f;
            wv[1] = (a0.y == 1) ? e0.y * ke + ce : 0.f;
            wv[2] = (a0.z == 1) ? e0.z * ke + ce : 0.f;
            wv[3] = (a0.w == 1) ? e0.w * ke + ce : 0.f;
            wv[4] = (a1.x == 1) ? e1.x * ke + ce : 0.f;
            wv[5] = (a1.y == 1) ? e1.y * ke + ce : 0.f;
            wv[6] = (a1.z == 1) ? e1.z * ke + ce : 0.f;
            wv[7] = (a1.w == 1) ? e1.w * ke + ce : 0.f;
            #pragma unroll
            for (int j = 0; j < 8; ++j) {
                unsigned short hi = f2b(wv[j]);
                ah[rt][j] = (short)hi;
                al[rt][j] = (short)f2b(wv[j] - b2f(hi));
            }
        }
        #pragma unroll
        for (int ft = 0; ft < 4; ++ft) {
            bf16x8 b = sHf[(ft * 16 + ks) * 64 + l];
            #pragma unroll
            for (int rt = 0; rt < 2; ++rt) {
                acc[rt][ft] = __builtin_amdgcn_mfma_f32_16x16x32_bf16(ah[rt], b, acc[rt][ft], 0, 0, 0);
                acc[rt][ft] = __builtin_amdgcn_mfma_f32_16x16x32_bf16(al[rt], b, acc[rt][ft], 0, 0, 0);
            }
        }
    }
    __syncthreads();   // done with sHf

    // ---- stage G3/G4 weights (hi/lo bf16 fragment order) ----
    bf16x8* sWtH = (bf16x8*)poolW;             // [6 nf][2 ks][64]
    bf16x8* sWtL = (bf16x8*)(poolW + 12288);
    bf16x8* sO1H = (bf16x8*)(poolW + 24576);   // [8 nf][3 ks][64]
    bf16x8* sO1L = (bf16x8*)(poolW + 49152);
    for (int e = t; e < 768; e += 256) {
        int nf = e >> 7, ks = (e >> 6) & 1, le = e & 63;
        int cc = le & 15, gg = le >> 4;
        bf16x8 vh, vl;
        #pragma unroll
        for (int j = 0; j < 8; ++j) {
            float vv = wt[(ks * 32 + gg * 8 + j) * TD + nf * 16 + cc];
            unsigned short hi = f2b(vv);
            vh[j] = (short)hi; vl[j] = (short)f2b(vv - b2f(hi));
        }
        sWtH[e] = vh; sWtL[e] = vl;
    }
    for (int e = t; e < 1536; e += 256) {
        int nf = e / 192, r = e % 192, ks = r >> 6, le = r & 63;
        int cc = le & 15, gg = le >> 4;
        bf16x8 vh, vl;
        #pragma unroll
        for (int j = 0; j < 8; ++j) {
            float vv = om1[(ks * 32 + gg * 8 + j) * H_ + nf * 16 + cc];
            unsigned short hi = f2b(vv);
            vh[j] = (short)hi; vl[j] = (short)f2b(vv - b2f(hi));
        }
        sO1H[e] = vh; sO1L[e] = vl;
    }
    __syncthreads();

    // ---- G3/G4 + epilogue, two 16-row passes per wave (per-wave scratch) ----
    char* Sw   = poolS + w * 11264;
    char* aggH = Sw;            // [16][144B]
    char* aggL = Sw + 2304;
    char* tyH  = Sw + 4608;     // [16][208B]
    char* tyL  = Sw + 7936;
    const float ob2 = sKe[2];
    const long long orow0 = (long long)li * O_ + o0 + w * 32;

    #pragma unroll
    for (int rf = 0; rf < 2; ++rf) {
        // agg pass rows -> hi/lo scratch (transpose via LDS)
        #pragma unroll
        for (int ft = 0; ft < 4; ++ft)
            #pragma unroll
            for (int reg = 0; reg < 4; ++reg) {
                int row = g * 4 + reg;
                float vv = acc[rf][ft][reg];
                unsigned short hi = f2b(vv);
                *(unsigned short*)(aggH + row * 144 + (ft * 16 + c) * 2) = hi;
                *(unsigned short*)(aggL + row * 144 + (ft * 16 + c) * 2) = f2b(vv - b2f(hi));
            }
        // G3: typed = agg @ Wt   (3-term split)
        f32x4 ty[6];
        #pragma unroll
        for (int nf = 0; nf < 6; ++nf) ty[nf] = (f32x4){0.f, 0.f, 0.f, 0.f};
        #pragma unroll
        for (int ks = 0; ks < 2; ++ks) {
            bf16x8 aH = *(const bf16x8*)(aggH + c * 144 + ks * 64 + g * 16);
            bf16x8 aL = *(const bf16x8*)(aggL + c * 144 + ks * 64 + g * 16);
            #pragma unroll
            for (int nf = 0; nf < 6; ++nf) {
                bf16x8 bH = sWtH[(nf * 2 + ks) * 64 + l];
                bf16x8 bL = sWtL[(nf * 2 + ks) * 64 + l];
                ty[nf] = __builtin_amdgcn_mfma_f32_16x16x32_bf16(aH, bH, ty[nf], 0, 0, 0);
                ty[nf] = __builtin_amdgcn_mfma_f32_16x16x32_bf16(aL, bH, ty[nf], 0, 0, 0);
                ty[nf] = __builtin_amdgcn_mfma_f32_16x16x32_bf16(aH, bL, ty[nf], 0, 0, 0);
            }
        }
        #pragma unroll
        for (int nf = 0; nf < 6; ++nf)
            #pragma unroll
            for (int reg = 0; reg < 4; ++reg) {
                int row = g * 4 + reg;
                float vv = ty[nf][reg];
                unsigned short hi = f2b(vv);
                *(unsigned short*)(tyH + row * 208 + (nf * 16 + c) * 2) = hi;
                *(unsigned short*)(tyL + row * 208 + (nf * 16 + c) * 2) = f2b(vv - b2f(hi));
            }
        // G4: h2 = typed @ om1   (3-term split)
        f32x4 h2[8];
        #pragma unroll
        for (int nf = 0; nf < 8; ++nf) h2[nf] = (f32x4){0.f, 0.f, 0.f, 0.f};
        #pragma unroll
        for (int ks = 0; ks < 3; ++ks) {
            bf16x8 aH = *(const bf16x8*)(tyH + c * 208 + ks * 64 + g * 16);
            bf16x8 aL = *(const bf16x8*)(tyL + c * 208 + ks * 64 + g * 16);
            #pragma unroll
            for (int nf = 0; nf < 8; ++nf) {
                bf16x8 bH = sO1H[(nf * 3 + ks) * 64 + l];
                bf16x8 bL = sO1L[(nf * 3 + ks) * 64 + l];
                h2[nf] = __builtin_amdgcn_mfma_f32_16x16x32_bf16(aH, bH, h2[nf], 0, 0, 0);
                h2[nf] = __builtin_amdgcn_mfma_f32_16x16x32_bf16(aL, bH, h2[nf], 0, 0, 0);
                h2[nf] = __builtin_amdgcn_mfma_f32_16x16x32_bf16(aH, bL, h2[nf], 0, 0, 0);
            }
        }
        // mas_w: elu -> *om2 -> reduce over c-lanes
        float p[4] = {0.f, 0.f, 0.f, 0.f};
        #pragma unroll
        for (int nf = 0; nf < 8; ++nf) {
            float o2 = sOm2[nf * 16 + c];
            float bb = sB1om[nf * 16 + c];
            #pragma unroll
            for (int reg = 0; reg < 4; ++reg)
                p[reg] += elu_f(h2[nf][reg] + bb) * o2;
        }
        #pragma unroll
        for (int reg = 0; reg < 4; ++reg) {
            #pragma unroll
            for (int off = 1; off < 16; off <<= 1)
                p[reg] += __shfl_xor(p[reg], off, 64);
            p[reg] += ob2;
        }
        // epilogue: leaky_relu(feat_opt + b2 + mas_w)
        #pragma unroll
        for (int nf2 = 0; nf2 < 2; ++nf2) {
            float b2v = sB2w0[nf2 * 16 + c];
            #pragma unroll
            for (int reg = 0; reg < 4; ++reg) {
                long long orow = orow0 + rf * 16 + g * 4 + reg;
                float val = fo[rf][nf2][reg] + b2v + p[reg];
                val = val >= 0.f ? val : 0.2f * val;
                out[orow * DOUT + nf2 * 16 + c] = val;
            }
        }
    }
}

// ---------------------------------------------------------------------------
extern "C" void kernel_launch(void* const* d_in, const int* in_sizes, int n_in,
                              void* d_out, int out_size, void* d_ws, size_t ws_size,
                              hipStream_t stream) {
    const float* feat0 = (const float*)d_in[0];
    const float* feat2 = (const float*)d_in[2];
    const int*   adj   = (const int*)d_in[3];
    const int*   bidx  = (const int*)d_in[4];
    const float* w0_w1 = (const float*)d_in[5];
    const float* w0_b1 = (const float*)d_in[6];
    const float* w0_w2 = (const float*)d_in[7];
    const float* w0_b2 = (const float*)d_in[8];
    const float* v     = (const float*)d_in[9];
    const float* coeff = (const float*)d_in[10];
    const float* e_w1  = (const float*)d_in[11];
    const float* e_b1  = (const float*)d_in[12];
    const float* e_w2  = (const float*)d_in[13];
    const float* e_b2  = (const float*)d_in[14];
    const float* om_w1 = (const float*)d_in[15];
    const float* om_b1 = (const float*)d_in[16];
    const float* om_w2 = (const float*)d_in[17];
    const float* om_b2 = (const float*)d_in[18];
    const float* feat1 = (const float*)d_in[1];
    float* out = (float*)d_out;
    float* ws  = (float*)d_ws;

    const int bsel = in_sizes[4];          // 32
    float* ws_scal = ws;                   // 2 floats
    float* ws_wt   = ws + 16;              // 64*96 floats

    k0_setup<<<1, 128, 0, stream>>>(e_w1, e_b1, e_w2, e_b2, coeff, v, ws_scal, ws_wt);
    mega<<<bsel * 16, 256, 0, stream>>>(feat0, feat2, adj, feat1, bidx,
                                        ws_scal, ws_wt,
                                        w0_w1, w0_b1, w0_w2, w0_b2,
                                        om_w1, om_b1, om_w2, om_b2, out);
}